// Round 2
// baseline (90.509 us; speedup 1.0000x reference)
//
#include <hip/hip_runtime.h>
#include <stdint.h>

// DeLaN forward, D=2, H1=64. Hybrid: sign-critical paths in fp32 VALU
// (bitwise identical to the passing R1 kernel), the two Jacobian GEMMs
// z_d = W1a @ (dR1 * W1[:,d]) offloaded to bf16 MFMA via the identity
//   z_d = 1.01*(IND @ M_d^T) - 0.01*S_d,  M_d[h,k] = W1a[h,k]*W1[k,d]
// with IND in {0,1} (exact in bf16) and M_d split hi/lo bf16.

typedef __attribute__((ext_vector_type(8))) short bf16x8;
typedef __attribute__((ext_vector_type(4))) float f32x4;

static __device__ __forceinline__ short f2bf(float f) {
    union { float f; uint32_t u; } v; v.f = f;
    uint32_t r = v.u + 0x7FFFu + ((v.u >> 16) & 1u);   // RNE
    return (short)(r >> 16);
}
static __device__ __forceinline__ float bf2f(short s) {
    union { uint32_t u; float f; } v; v.u = ((uint32_t)(uint16_t)s) << 16;
    return v.f;
}

__global__ __launch_bounds__(256) void delan_fwd(
    const float* __restrict__ x,
    const float* __restrict__ W1,  const float* __restrict__ b1,
    const float* __restrict__ W1a, const float* __restrict__ b1a,
    const float* __restrict__ W2,  const float* __restrict__ b2,
    const float* __restrict__ W3,  const float* __restrict__ b3,
    const float* __restrict__ W4,  const float* __restrict__ b4,
    float* __restrict__ out, int n_total)
{
    // 32 frags x (64 lanes x 8 bf16) = 32 KiB. fid = hc*8 + m*4 + split*2 + kh
    __shared__ short mfrag[32 * 64 * 8];
    __shared__ float S_lds[2][64];
    __shared__ float pr_lds[256 * 6];

    const int tid  = threadIdx.x;
    const int lane = tid & 63;
    const int wid  = tid >> 6;
    const int n    = blockIdx.x * 256 + tid;
    const int nc   = (n < n_total) ? n : (n_total - 1);

    const float x0 = x[6*nc+0], x1 = x[6*nc+1];
    const float x2 = x[6*nc+2], x3 = x[6*nc+3];
    const float x4 = x[6*nc+4], x5 = x[6*nc+5];

    // ---- P0: layer 1 (fp32, identical arithmetic to R1) ----
    float h1[64];
    uint32_t m1lo = 0u, m1hi = 0u;
#pragma unroll
    for (int k = 0; k < 64; ++k) {
        const float w0 = W1[2*k], w1 = W1[2*k+1];
        const float pre = fmaf(w0, x0, fmaf(w1, x1, b1[k]));
        const bool pos = pre > 0.0f;
        h1[k] = pos ? pre : 0.01f * pre;
        if (k < 32) m1lo |= pos ? (1u << k) : 0u;
        else        m1hi |= pos ? (1u << (k - 32)) : 0u;
    }

    // ---- P1: h2pre chain + g/l/oo dots (fp32, identical to R1) ----
    float g0 = b2[0], g1 = b2[1];
    float l0 = b3[0], l1 = b3[1];
    float oo = b4[0];
    uint32_t m2lo = 0u, m2hi = 0u;
#pragma unroll 4
    for (int h = 0; h < 64; ++h) {
        float ah = b1a[h];
        const float* __restrict__ wrow = W1a + h * 64;   // wave-uniform -> s_loads
#pragma unroll
        for (int k = 0; k < 64; ++k) ah = fmaf(wrow[k], h1[k], ah);
        const bool pos = ah > 0.0f;
        const float h2 = pos ? ah : 0.01f * ah;
        if (h < 32) m2lo |= pos ? (1u << h) : 0u;
        else        m2hi |= pos ? (1u << (h - 32)) : 0u;
        g0 = fmaf(W2[h], h2, g0);      g1 = fmaf(W2[64 + h], h2, g1);
        l0 = fmaf(W3[h], h2, l0);      l1 = fmaf(W3[64 + h], h2, l1);
        oo = fmaf(W4[h], h2, oo);
    }

    // ---- Build M0/M1 hi/lo B-fragments in LDS (wave wid owns hc = wid) ----
    {
        const int hc   = wid;
        const int hcol = hc * 16 + (lane & 15);           // B col -> h
        const int kbl  = (lane >> 4) * 8;                 // k-chunk within 32
        float Sp0 = 0.f, Sp1 = 0.f;
#pragma unroll
        for (int kh = 0; kh < 2; ++kh) {
            const int kb = kh * 32 + kbl;
            float wa[8], wb[16];
            *(float4*)&wa[0]  = *(const float4*)(W1a + hcol * 64 + kb);
            *(float4*)&wa[4]  = *(const float4*)(W1a + hcol * 64 + kb + 4);
            *(float4*)&wb[0]  = *(const float4*)(W1 + 2 * kb);
            *(float4*)&wb[4]  = *(const float4*)(W1 + 2 * kb + 4);
            *(float4*)&wb[8]  = *(const float4*)(W1 + 2 * kb + 8);
            *(float4*)&wb[12] = *(const float4*)(W1 + 2 * kb + 12);
            bf16x8 hi0, lo0, hi1, lo1;
#pragma unroll
            for (int j = 0; j < 8; ++j) {
                const float mv0 = wa[j] * wb[2*j + 0];
                const float mv1 = wa[j] * wb[2*j + 1];
                Sp0 += mv0; Sp1 += mv1;
                const short a = f2bf(mv0); hi0[j] = a; lo0[j] = f2bf(mv0 - bf2f(a));
                const short b = f2bf(mv1); hi1[j] = b; lo1[j] = f2bf(mv1 - bf2f(b));
            }
            *(bf16x8*)&mfrag[((hc*8 + 0 + kh)*64 + lane)*8] = hi0;  // m0 hi
            *(bf16x8*)&mfrag[((hc*8 + 2 + kh)*64 + lane)*8] = lo0;  // m0 lo
            *(bf16x8*)&mfrag[((hc*8 + 4 + kh)*64 + lane)*8] = hi1;  // m1 hi
            *(bf16x8*)&mfrag[((hc*8 + 6 + kh)*64 + lane)*8] = lo1;  // m1 lo
        }
        Sp0 += __shfl_xor(Sp0, 16); Sp0 += __shfl_xor(Sp0, 32);
        Sp1 += __shfl_xor(Sp1, 16); Sp1 += __shfl_xor(Sp1, 32);
        if (lane < 16) { S_lds[0][hc*16 + lane] = Sp0; S_lds[1][hc*16 + lane] = Sp1; }
    }
    __syncthreads();

    // ---- P2: MFMA z-GEMMs + masked W3/W4 dots ----
    float wv30[4], wv31[4], wv4[4], zb0[4], zb1[4];
#pragma unroll
    for (int hc = 0; hc < 4; ++hc) {
        const int hcol = hc * 16 + (lane & 15);
        wv30[hc] = W3[hcol]; wv31[hc] = W3[64 + hcol]; wv4[hc] = W4[hcol];
        zb0[hc] = -0.01f * S_lds[0][hcol];
        zb1[hc] = -0.01f * S_lds[1][hcol];
    }

    const int kbl = (lane >> 4) * 8;
#pragma unroll
    for (int t = 0; t < 4; ++t) {
        // A fragment: IND rows = samples t*16 + (lane&15)
        const int arow = t * 16 + (lane & 15);
        const uint32_t aw0 = (uint32_t)__shfl((int)m1lo, arow);
        const uint32_t aw1 = (uint32_t)__shfl((int)m1hi, arow);
        bf16x8 ind0, ind1;
#pragma unroll
        for (int j = 0; j < 8; ++j) {
            ind0[j] = (short)(((aw0 >> (kbl + j)) & 1u) ? 0x3F80 : 0);
            ind1[j] = (short)(((aw1 >> (kbl + j)) & 1u) ? 0x3F80 : 0);
        }
        // dr2 masks for this tile's C rows = samples t*16 + (lane>>4)*4 + r
        uint32_t q2l[4], q2h[4];
#pragma unroll
        for (int r = 0; r < 4; ++r) {
            const int src = t * 16 + (lane >> 4) * 4 + r;
            q2l[r] = (uint32_t)__shfl((int)m2lo, src);
            q2h[r] = (uint32_t)__shfl((int)m2hi, src);
        }

        float acc[6][4];   // p00,p01,p10,p11,r0,r1 per C-row
#pragma unroll
        for (int d = 0; d < 6; ++d)
#pragma unroll
            for (int r = 0; r < 4; ++r) acc[d][r] = 0.f;

#pragma unroll
        for (int hc = 0; hc < 4; ++hc) {
#define LDF(f) (*(const bf16x8*)&mfrag[(((hc*8) + (f))*64 + lane)*8])
            f32x4 C0 = {0.f, 0.f, 0.f, 0.f};
            C0 = __builtin_amdgcn_mfma_f32_16x16x32_bf16(ind0, LDF(0), C0, 0, 0, 0);
            C0 = __builtin_amdgcn_mfma_f32_16x16x32_bf16(ind1, LDF(1), C0, 0, 0, 0);
            C0 = __builtin_amdgcn_mfma_f32_16x16x32_bf16(ind0, LDF(2), C0, 0, 0, 0);
            C0 = __builtin_amdgcn_mfma_f32_16x16x32_bf16(ind1, LDF(3), C0, 0, 0, 0);
            f32x4 C1 = {0.f, 0.f, 0.f, 0.f};
            C1 = __builtin_amdgcn_mfma_f32_16x16x32_bf16(ind0, LDF(4), C1, 0, 0, 0);
            C1 = __builtin_amdgcn_mfma_f32_16x16x32_bf16(ind1, LDF(5), C1, 0, 0, 0);
            C1 = __builtin_amdgcn_mfma_f32_16x16x32_bf16(ind0, LDF(6), C1, 0, 0, 0);
            C1 = __builtin_amdgcn_mfma_f32_16x16x32_bf16(ind1, LDF(7), C1, 0, 0, 0);
#undef LDF
            const uint32_t sh = (uint32_t)(((hc & 1) << 4) + (lane & 15));
#pragma unroll
            for (int r = 0; r < 4; ++r) {
                const uint32_t w = (hc < 2) ? q2l[r] : q2h[r];
                const bool pos = ((w >> sh) & 1u) != 0u;
                const float z0 = fmaf(1.01f, C0[r], zb0[hc]);
                const float z1 = fmaf(1.01f, C1[r], zb1[hc]);
                const float d0 = pos ? z0 : -0.01f * z0;
                const float d1 = pos ? z1 : -0.01f * z1;
                acc[0][r] = fmaf(wv30[hc], d0, acc[0][r]);
                acc[1][r] = fmaf(wv30[hc], d1, acc[1][r]);
                acc[2][r] = fmaf(wv31[hc], d0, acc[2][r]);
                acc[3][r] = fmaf(wv31[hc], d1, acc[3][r]);
                acc[4][r] = fmaf(wv4[hc],  d0, acc[4][r]);
                acc[5][r] = fmaf(wv4[hc],  d1, acc[5][r]);
            }
        }
        // reduce over the 16 h-col lanes (butterfly; DPP-able)
#pragma unroll
        for (int d = 0; d < 6; ++d)
#pragma unroll
            for (int r = 0; r < 4; ++r) {
                float v = acc[d][r];
                v += __shfl_xor(v, 1);
                v += __shfl_xor(v, 2);
                v += __shfl_xor(v, 4);
                v += __shfl_xor(v, 8);
                acc[d][r] = v;
            }
        if ((lane & 15) == 0) {
            const int sbase = wid * 64 + t * 16 + (lane >> 4) * 4;
#pragma unroll
            for (int r = 0; r < 4; ++r)
#pragma unroll
                for (int d = 0; d < 6; ++d)
                    pr_lds[(sbase + r) * 6 + d] = acc[d][r];
        }
    }
    __syncthreads();

    const float p00 = pr_lds[tid*6 + 0];
    const float p01 = pr_lds[tid*6 + 1];
    const float p10 = pr_lds[tid*6 + 2];
    const float p11 = pr_lds[tid*6 + 3];
    const float r0  = pr_lds[tid*6 + 4];
    const float r1  = pr_lds[tid*6 + 5];

    // ---- Tail: 2x2 algebra (identical to R1) ----
    const float ld0 = fmaxf(l0, 0.0f);
    const float ld1 = fmaxf(l1, 0.0f);
    const float dr30 = (l0 > 0.0f) ? 1.0f : 0.0f;
    const float dr31 = (l1 > 0.0f) ? 1.0f : 0.0f;

    const float da00 = dr30 * p00, da01 = dr30 * p01;
    const float da10 = dr31 * p10, da11 = dr31 * p11;

    const float l00 = ld0, l10 = oo, l11 = ld1;

    const float m00 = da00 * x2 + da01 * x3;
    const float m11 = da10 * x2 + da11 * x3;
    const float m10 = r0  * x2 + r1  * x3;

    const float eps = 1e-5f;
    const float Hm00 = fmaf(l00, l00, eps);
    const float Hm01 = l00 * l10;
    const float Hm11 = fmaf(l10, l10, fmaf(l11, l11, eps));

    const float dH00 = 2.0f * l00 * m00;
    const float dH01 = fmaf(l00, m10, l10 * m00);
    const float dH11 = 2.0f * fmaf(l10, m10, l11 * m11);

    const float x22 = x2 * x2, x23 = x2 * x3, x33 = x3 * x3;
    const float quad0 = 2.0f * (da00 * l00 * x22
                      + (fmaf(da00, l10, r0 * l00)) * x23
                      + (fmaf(r0, l10, da10 * l11)) * x33);
    const float quad1 = 2.0f * (da01 * l00 * x22
                      + (fmaf(da01, l10, r1 * l00)) * x23
                      + (fmaf(r1, l10, da11 * l11)) * x33);

    const float c0 = fmaf(dH00, x2, dH01 * x3) - 0.5f * quad0;
    const float c1 = fmaf(dH01, x2, dH11 * x3) - 0.5f * quad1;

    const float tau0 = fmaf(Hm00, x4, Hm01 * x5) + c0 + g0;
    const float tau1 = fmaf(Hm01, x4, Hm11 * x5) + c1 + g1;

    if (n < n_total) {
        const long long N = n_total;
        float2* tau_out = (float2*)(out) + n;
        float4* hm_out  = (float4*)(out + 2 * N) + n;
        float2* c_out   = (float2*)(out + 6 * N) + n;
        float2* g_out   = (float2*)(out + 8 * N) + n;
        *tau_out = make_float2(tau0, tau1);
        *hm_out  = make_float4(Hm00, Hm01, Hm01, Hm11);
        *c_out   = make_float2(c0, c1);
        *g_out   = make_float2(g0, g1);
    }
}

extern "C" void kernel_launch(void* const* d_in, const int* in_sizes, int n_in,
                              void* d_out, int out_size, void* d_ws, size_t ws_size,
                              hipStream_t stream) {
    const float* x   = (const float*)d_in[0];
    const float* W1  = (const float*)d_in[1];
    const float* b1  = (const float*)d_in[2];
    const float* W1a = (const float*)d_in[3];
    const float* b1a = (const float*)d_in[4];
    const float* W2  = (const float*)d_in[5];
    const float* b2  = (const float*)d_in[6];
    const float* W3  = (const float*)d_in[7];
    const float* b3  = (const float*)d_in[8];
    const float* W4  = (const float*)d_in[9];
    const float* b4  = (const float*)d_in[10];
    float* out = (float*)d_out;

    const int n_total = in_sizes[0] / 6;
    const int block = 256;
    const int grid = (n_total + block - 1) / block;
    delan_fwd<<<grid, block, 0, stream>>>(x, W1, b1, W1a, b1a, W2, b2,
                                          W3, b3, W4, b4, out, n_total);
}

// Round 3
// 31.122 us; speedup vs baseline: 2.9082x; 2.9082x over previous
//
#include <hip/hip_runtime.h>
#include <stdint.h>

// DeLaN forward, D=2, H1=64 — full-MFMA formulation.
// Per 16-sample tile, lane (p = l&15, q = l>>4) computes pre/h1/u for sample
// p, k-chunk q*8..q*8+7 directly in MFMA B-layout. A = W1a as constant f16
// hi/lo fragments in LDS. C[h,sample]: row=h=(l>>4)*4+r, col=sample=l&15
// (layout proven by R2's passing run). ah (sign-critical) uses hi/lo x hi/lo
// (rel err ~1e-7, fp32-like); z0/z1 use hi-only (continuous path, ~1e-3 rel).

typedef __attribute__((ext_vector_type(8))) _Float16 f16x8;
typedef __attribute__((ext_vector_type(4))) float f32x4;

#define MFMA16(A, B, C) __builtin_amdgcn_mfma_f32_16x16x32_f16((A), (B), (C), 0, 0, 0)

__global__ __launch_bounds__(256, 3) void delan_fwd(
    const float* __restrict__ x,
    const float* __restrict__ W1,  const float* __restrict__ b1,
    const float* __restrict__ W1a, const float* __restrict__ b1a,
    const float* __restrict__ W2,  const float* __restrict__ b2,
    const float* __restrict__ W3,  const float* __restrict__ b3,
    const float* __restrict__ W4,  const float* __restrict__ b4,
    float* __restrict__ out, int n_total)
{
    __shared__ _Float16 afrag[2][4][2][64][8];  // [split][htile][khalf][lane][8] = 16 KB
    __shared__ float w1b1[64][4];               // {W1[k,0], W1[k,1], b1[k], 0}
    __shared__ float cst[6][64];                // W2c0,W2c1,W3c0,W3c1,W4,b1a

    const int tid  = threadIdx.x;
    const int lane = tid & 63;
    const int wid  = tid >> 6;
    const int p    = lane & 15;
    const int qrt  = lane >> 4;
    const int n    = blockIdx.x * 256 + tid;
    const int nc   = (n < n_total) ? n : (n_total - 1);

    const float2 xa = *(const float2*)(x + 6 * nc);
    const float2 xb = *(const float2*)(x + 6 * nc + 2);
    const float2 xc = *(const float2*)(x + 6 * nc + 4);
    const float x0 = xa.x, x1 = xa.y;
    const float x2 = xb.x, x3 = xb.y;
    const float x4 = xc.x, x5 = xc.y;

    // ---- Block-constant build ----
    if (tid < 64) {
        const int k = tid;
        w1b1[k][0] = W1[2*k]; w1b1[k][1] = W1[2*k+1]; w1b1[k][2] = b1[k]; w1b1[k][3] = 0.f;
        cst[0][k] = W2[k];      cst[1][k] = W2[64 + k];
        cst[2][k] = W3[k];      cst[3][k] = W3[64 + k];
        cst[4][k] = W4[k];      cst[5][k] = b1a[k];
    }
    {
        const int ht = wid;                 // wave wid builds h-tile wid
#pragma unroll
        for (int kh = 0; kh < 2; ++kh) {
            const int row = ht * 16 + p;
            const int kb  = kh * 32 + qrt * 8;
            float wv[8];
            *(float4*)&wv[0] = *(const float4*)(W1a + row * 64 + kb);
            *(float4*)&wv[4] = *(const float4*)(W1a + row * 64 + kb + 4);
            f16x8 hi, lo;
#pragma unroll
            for (int j = 0; j < 8; ++j) {
                const _Float16 h = (_Float16)wv[j];
                hi[j] = h;
                lo[j] = (_Float16)((wv[j] - (float)h) * 4096.0f);
            }
            *(f16x8*)&afrag[0][ht][kh][lane][0] = hi;
            *(f16x8*)&afrag[1][ht][kh][lane][0] = lo;
        }
    }
    __syncthreads();

    float fg0=0.f, fg1=0.f, fl0=0.f, fl1=0.f, foo=0.f;
    float fp00=0.f, fp01=0.f, fp10=0.f, fp11=0.f, fr0=0.f, fr1=0.f;

#pragma unroll
    for (int t = 0; t < 4; ++t) {
        // ---- Phase A: build B-fragments for sample tile t ----
        const float q0t = __shfl(x0, t * 16 + p);
        const float q1t = __shfl(x1, t * 16 + p);
        f16x8 Bhh[2], Bhl[2], Bu0[2], Bu1[2];
#pragma unroll
        for (int kh = 0; kh < 2; ++kh) {
#pragma unroll
            for (int j = 0; j < 8; ++j) {
                const int k = kh * 32 + qrt * 8 + j;
                const f32x4 wv = *(const f32x4*)&w1b1[k][0];
                const float pre = fmaf(wv[0], q0t, fmaf(wv[1], q1t, wv[2]));
                const bool pos = pre > 0.0f;
                const float h1v = pos ? pre : 0.01f * pre;
                const float u0v = pos ? wv[0] : -0.01f * wv[0];
                const float u1v = pos ? wv[1] : -0.01f * wv[1];
                const _Float16 hh = (_Float16)h1v;
                Bhh[kh][j] = hh;
                Bhl[kh][j] = (_Float16)((h1v - (float)hh) * 4096.0f);
                Bu0[kh][j] = (_Float16)u0v;
                Bu1[kh][j] = (_Float16)u1v;
            }
        }

        // ---- Phase B: MFMA over 4 h-tiles + fused epilogue ----
        float ag0=0.f, ag1=0.f, al0=0.f, al1=0.f, aoo=0.f;
        float ap00=0.f, ap01=0.f, ap10=0.f, ap11=0.f, ar0=0.f, ar1=0.f;
#pragma unroll
        for (int ht = 0; ht < 4; ++ht) {
            const f16x8 Ah0 = *(const f16x8*)&afrag[0][ht][0][lane][0];
            const f16x8 Ah1 = *(const f16x8*)&afrag[0][ht][1][lane][0];
            const f16x8 Al0 = *(const f16x8*)&afrag[1][ht][0][lane][0];
            const f16x8 Al1 = *(const f16x8*)&afrag[1][ht][1][lane][0];
            f32x4 Chi = {0.f,0.f,0.f,0.f}, Clo = {0.f,0.f,0.f,0.f};
            f32x4 Cz0 = {0.f,0.f,0.f,0.f}, Cz1 = {0.f,0.f,0.f,0.f};
            Chi = MFMA16(Ah0, Bhh[0], Chi);  Chi = MFMA16(Ah1, Bhh[1], Chi);
            Clo = MFMA16(Ah0, Bhl[0], Clo);  Clo = MFMA16(Ah1, Bhl[1], Clo);
            Clo = MFMA16(Al0, Bhh[0], Clo);  Clo = MFMA16(Al1, Bhh[1], Clo);
            Cz0 = MFMA16(Ah0, Bu0[0], Cz0);  Cz0 = MFMA16(Ah1, Bu0[1], Cz0);
            Cz1 = MFMA16(Ah0, Bu1[0], Cz1);  Cz1 = MFMA16(Ah1, Bu1[1], Cz1);

            const int hb = ht * 16 + qrt * 4;
            const f32x4 w2a  = *(const f32x4*)&cst[0][hb];
            const f32x4 w2b  = *(const f32x4*)&cst[1][hb];
            const f32x4 w3a  = *(const f32x4*)&cst[2][hb];
            const f32x4 w3b  = *(const f32x4*)&cst[3][hb];
            const f32x4 w4v  = *(const f32x4*)&cst[4][hb];
            const f32x4 b1av = *(const f32x4*)&cst[5][hb];
#pragma unroll
            for (int r = 0; r < 4; ++r) {
                const float ah = fmaf(2.44140625e-4f, Clo[r], Chi[r]) + b1av[r];
                const bool pos = ah > 0.0f;
                const float h2 = pos ? ah : 0.01f * ah;
                ag0 = fmaf(w2a[r], h2, ag0);   ag1 = fmaf(w2b[r], h2, ag1);
                al0 = fmaf(w3a[r], h2, al0);   al1 = fmaf(w3b[r], h2, al1);
                aoo = fmaf(w4v[r], h2, aoo);
                const float z0 = Cz0[r], z1 = Cz1[r];
                const float d0 = pos ? z0 : -0.01f * z0;
                const float d1 = pos ? z1 : -0.01f * z1;
                ap00 = fmaf(w3a[r], d0, ap00); ap01 = fmaf(w3a[r], d1, ap01);
                ap10 = fmaf(w3b[r], d0, ap10); ap11 = fmaf(w3b[r], d1, ap11);
                ar0  = fmaf(w4v[r], d0, ar0);  ar1  = fmaf(w4v[r], d1, ar1);
            }
        }

        // ---- Reduce over the 4 h-quarters (lanes p, p+16, p+32, p+48) ----
#define RED(v) { v += __shfl_xor(v, 16); v += __shfl_xor(v, 32); }
        RED(ag0) RED(ag1) RED(al0) RED(al1) RED(aoo)
        RED(ap00) RED(ap01) RED(ap10) RED(ap11) RED(ar0) RED(ar1)
#undef RED
        // Owner lane of sample t*16+p is lane t*16+p itself (qrt == t).
        if (qrt == t) {
            fg0 = ag0; fg1 = ag1; fl0 = al0; fl1 = al1; foo = aoo;
            fp00 = ap00; fp01 = ap01; fp10 = ap10; fp11 = ap11;
            fr0 = ar0; fr1 = ar1;
        }
    }

    // ---- Tail: biases + 2x2 algebra (identical to R1) ----
    const float g0 = fg0 + b2[0], g1 = fg1 + b2[1];
    const float l0 = fl0 + b3[0], l1 = fl1 + b3[1];
    const float oo = foo + b4[0];
    const float p00 = fp00, p01 = fp01, p10 = fp10, p11 = fp11;
    const float r0 = fr0, r1 = fr1;

    const float ld0 = fmaxf(l0, 0.0f);
    const float ld1 = fmaxf(l1, 0.0f);
    const float dr30 = (l0 > 0.0f) ? 1.0f : 0.0f;
    const float dr31 = (l1 > 0.0f) ? 1.0f : 0.0f;

    const float da00 = dr30 * p00, da01 = dr30 * p01;
    const float da10 = dr31 * p10, da11 = dr31 * p11;

    const float l00 = ld0, l10 = oo, l11 = ld1;

    const float m00 = da00 * x2 + da01 * x3;
    const float m11 = da10 * x2 + da11 * x3;
    const float m10 = r0  * x2 + r1  * x3;

    const float eps = 1e-5f;
    const float Hm00 = fmaf(l00, l00, eps);
    const float Hm01 = l00 * l10;
    const float Hm11 = fmaf(l10, l10, fmaf(l11, l11, eps));

    const float dH00 = 2.0f * l00 * m00;
    const float dH01 = fmaf(l00, m10, l10 * m00);
    const float dH11 = 2.0f * fmaf(l10, m10, l11 * m11);

    const float x22 = x2 * x2, x23 = x2 * x3, x33 = x3 * x3;
    const float quad0 = 2.0f * (da00 * l00 * x22
                      + (fmaf(da00, l10, r0 * l00)) * x23
                      + (fmaf(r0, l10, da10 * l11)) * x33);
    const float quad1 = 2.0f * (da01 * l00 * x22
                      + (fmaf(da01, l10, r1 * l00)) * x23
                      + (fmaf(r1, l10, da11 * l11)) * x33);

    const float c0 = fmaf(dH00, x2, dH01 * x3) - 0.5f * quad0;
    const float c1 = fmaf(dH01, x2, dH11 * x3) - 0.5f * quad1;

    const float tau0 = fmaf(Hm00, x4, Hm01 * x5) + c0 + g0;
    const float tau1 = fmaf(Hm01, x4, Hm11 * x5) + c1 + g1;

    if (n < n_total) {
        const long long N = n_total;
        float2* tau_out = (float2*)(out) + n;
        float4* hm_out  = (float4*)(out + 2 * N) + n;
        float2* c_out   = (float2*)(out + 6 * N) + n;
        float2* g_out   = (float2*)(out + 8 * N) + n;
        *tau_out = make_float2(tau0, tau1);
        *hm_out  = make_float4(Hm00, Hm01, Hm01, Hm11);
        *c_out   = make_float2(c0, c1);
        *g_out   = make_float2(g0, g1);
    }
}

extern "C" void kernel_launch(void* const* d_in, const int* in_sizes, int n_in,
                              void* d_out, int out_size, void* d_ws, size_t ws_size,
                              hipStream_t stream) {
    const float* x   = (const float*)d_in[0];
    const float* W1  = (const float*)d_in[1];
    const float* b1  = (const float*)d_in[2];
    const float* W1a = (const float*)d_in[3];
    const float* b1a = (const float*)d_in[4];
    const float* W2  = (const float*)d_in[5];
    const float* b2  = (const float*)d_in[6];
    const float* W3  = (const float*)d_in[7];
    const float* b3  = (const float*)d_in[8];
    const float* W4  = (const float*)d_in[9];
    const float* b4  = (const float*)d_in[10];
    float* out = (float*)d_out;

    const int n_total = in_sizes[0] / 6;
    const int block = 256;
    const int grid = (n_total + block - 1) / block;
    delan_fwd<<<grid, block, 0, stream>>>(x, W1, b1, W1a, b1a, W2, b2,
                                          W3, b3, W4, b4, out, n_total);
}

// Round 4
// 30.313 us; speedup vs baseline: 2.9858x; 1.0267x over previous
//
#include <hip/hip_runtime.h>
#include <stdint.h>

// DeLaN forward, D=2, H1=64 — full-MFMA formulation (R3 structure, proven
// absmax 0.0078) + packed-VALU Phase A, permlane reductions, b1a C-init,
// occupancy 4. Math/layout identical to R3 except benign rounding changes
// on continuous paths (RTZ packing; residual-corrected hi/lo unaffected).

typedef __attribute__((ext_vector_type(8))) _Float16 f16x8;
typedef __attribute__((ext_vector_type(4))) float f32x4;
typedef __attribute__((ext_vector_type(2))) float f32x2;
typedef __attribute__((ext_vector_type(4))) unsigned int u32x4;

#define MFMA16(A,B,C) __builtin_amdgcn_mfma_f32_16x16x32_f16((A),(B),(C),0,0,0)

static __device__ __forceinline__ f32x2 pk_fma(f32x2 a, f32x2 b, f32x2 c) {
    f32x2 d;
    asm("v_pk_fma_f32 %0, %1, %2, %3" : "=v"(d) : "v"(a), "v"(b), "v"(c));
    return d;
}
static __device__ __forceinline__ f32x2 pk_mul(f32x2 a, f32x2 b) {
    f32x2 d;
    asm("v_pk_mul_f32 %0, %1, %2" : "=v"(d) : "v"(a), "v"(b));
    return d;
}
static __device__ __forceinline__ unsigned pkmul16(unsigned a, unsigned b) {
    unsigned d;
    asm("v_pk_mul_f16 %0, %1, %2" : "=v"(d) : "v"(a), "v"(b));
    return d;
}
// sum over the 4 lanes {l, l^16, l^32, l^48} (result in every lane), pure VALU
static __device__ __forceinline__ float qsum(float v) {
    float a = v, b = v;
    asm("v_permlane16_swap_b32 %0, %1" : "+v"(a), "+v"(b));
    const float s = a + b;
    float c = s, d = s;
    asm("v_permlane32_swap_b32 %0, %1" : "+v"(c), "+v"(d));
    return c + d;
}

__global__ __launch_bounds__(256, 4) void delan_fwd(
    const float* __restrict__ x,
    const float* __restrict__ W1,  const float* __restrict__ b1,
    const float* __restrict__ W1a, const float* __restrict__ b1a,
    const float* __restrict__ W2,  const float* __restrict__ b2,
    const float* __restrict__ W3,  const float* __restrict__ b3,
    const float* __restrict__ W4,  const float* __restrict__ b4,
    float* __restrict__ out, int n_total)
{
    __shared__ _Float16 afrag[2][4][2][64][8];  // 16 KB: [split][htile][khalf][lane][8]
    __shared__ float w0s[64], w1s[64], bs[64];  // W1 SoA + b1
    __shared__ float cst[6][64];                // W2c0,W2c1,W3c0,W3c1,W4,b1a

    const int tid  = threadIdx.x;
    const int lane = tid & 63;
    const int wid  = tid >> 6;
    const int p    = lane & 15;
    const int qrt  = lane >> 4;
    const int n    = blockIdx.x * 256 + tid;
    const int nc   = (n < n_total) ? n : (n_total - 1);

    const float2 xa = *(const float2*)(x + 6 * nc);
    const float2 xb = *(const float2*)(x + 6 * nc + 2);
    const float2 xc = *(const float2*)(x + 6 * nc + 4);
    const float x0 = xa.x, x1 = xa.y;
    const float x2 = xb.x, x3 = xb.y;
    const float x4 = xc.x, x5 = xc.y;

    // ---- Block-constant build ----
    if (tid < 64) {
        const int k = tid;
        w0s[k] = W1[2*k]; w1s[k] = W1[2*k+1]; bs[k] = b1[k];
        cst[0][k] = W2[k];      cst[1][k] = W2[64 + k];
        cst[2][k] = W3[k];      cst[3][k] = W3[64 + k];
        cst[4][k] = W4[k];      cst[5][k] = b1a[k];
    }
    {
        const int ht = wid;                 // wave wid builds h-tile wid
#pragma unroll
        for (int kh = 0; kh < 2; ++kh) {
            const int row = ht * 16 + p;
            const int kb  = kh * 32 + qrt * 8;
            float wv[8];
            *(float4*)&wv[0] = *(const float4*)(W1a + row * 64 + kb);
            *(float4*)&wv[4] = *(const float4*)(W1a + row * 64 + kb + 4);
            f16x8 hi, lo;
#pragma unroll
            for (int j = 0; j < 8; ++j) {
                const _Float16 h = (_Float16)wv[j];
                hi[j] = h;
                lo[j] = (_Float16)((wv[j] - (float)h) * 4096.0f);
            }
            *(f16x8*)&afrag[0][ht][kh][lane][0] = hi;
            *(f16x8*)&afrag[1][ht][kh][lane][0] = lo;
        }
    }
    __syncthreads();

    const f32x2 c4096  = {4096.0f, 4096.0f};
    const f32x2 cm4096 = {-4096.0f, -4096.0f};

    float fg0=0.f, fg1=0.f, fl0=0.f, fl1=0.f, foo=0.f;
    float fp00=0.f, fp01=0.f, fp10=0.f, fp11=0.f, fr0=0.f, fr1=0.f;

#pragma unroll
    for (int t = 0; t < 4; ++t) {
        // ---- Phase A: build B-fragments for sample tile t (packed) ----
        const float q0t = __shfl(x0, t * 16 + p);
        const float q1t = __shfl(x1, t * 16 + p);
        const f32x2 q00 = {q0t, q0t};
        const f32x2 q11 = {q1t, q1t};
        u32x4 Bhh[2], Bhl[2], Bu0[2], Bu1[2];
#pragma unroll
        for (int kh = 0; kh < 2; ++kh) {
            const int kb = kh * 32 + qrt * 8;
#pragma unroll
            for (int c = 0; c < 4; ++c) {
                const f32x2 w0p = *(const f32x2*)&w0s[kb + 2*c];
                const f32x2 w1p = *(const f32x2*)&w1s[kb + 2*c];
                const f32x2 bp  = *(const f32x2*)&bs [kb + 2*c];
                const f32x2 prep = pk_fma(w0p, q00, pk_fma(w1p, q11, bp));
                const bool pos0 = prep.x > 0.0f;
                const bool pos1 = prep.y > 0.0f;
                // u fragments: f16(W1) * f16(dr), dr in {1.0, -0.01}
                const unsigned mlo = pos0 ? 0x00003C00u : 0x0000A11Fu;
                const unsigned mhi = pos1 ? 0x3C000000u : 0xA11F0000u;
                const unsigned drw = mlo | mhi;
                const unsigned p0w = __builtin_bit_cast(unsigned,
                    __builtin_amdgcn_cvt_pkrtz(w0p.x, w0p.y));
                const unsigned p1w = __builtin_bit_cast(unsigned,
                    __builtin_amdgcn_cvt_pkrtz(w1p.x, w1p.y));
                Bu0[kh][c] = pkmul16(p0w, drw);
                Bu1[kh][c] = pkmul16(p1w, drw);
                // h1 hi/lo split (residual-corrected, fp32-accurate path)
                f32x2 sp;
                sp.x = pos0 ? 1.0f : 0.01f;
                sp.y = pos1 ? 1.0f : 0.01f;
                const f32x2 h1p = pk_mul(prep, sp);
                const auto hhv = __builtin_amdgcn_cvt_pkrtz(h1p.x, h1p.y);
                Bhh[kh][c] = __builtin_bit_cast(unsigned, hhv);
                f32x2 hf;
                hf.x = (float)hhv[0];
                hf.y = (float)hhv[1];
                const f32x2 tt = pk_mul(h1p, c4096);
                const f32x2 rp = pk_fma(hf, cm4096, tt);   // (h1 - hh) * 4096
                Bhl[kh][c] = __builtin_bit_cast(unsigned,
                    __builtin_amdgcn_cvt_pkrtz(rp.x, rp.y));
            }
        }

        // ---- Phase B: MFMA over 4 h-tiles + fused epilogue ----
        float ag0=0.f, ag1=0.f, al0=0.f, al1=0.f, aoo=0.f;
        float ap00=0.f, ap01=0.f, ap10=0.f, ap11=0.f, ar0=0.f, ar1=0.f;
#pragma unroll
        for (int ht = 0; ht < 4; ++ht) {
            const f16x8 Ah0 = *(const f16x8*)&afrag[0][ht][0][lane][0];
            const f16x8 Ah1 = *(const f16x8*)&afrag[0][ht][1][lane][0];
            const f16x8 Al0 = *(const f16x8*)&afrag[1][ht][0][lane][0];
            const f16x8 Al1 = *(const f16x8*)&afrag[1][ht][1][lane][0];
            const f16x8 bh0 = __builtin_bit_cast(f16x8, Bhh[0]);
            const f16x8 bh1 = __builtin_bit_cast(f16x8, Bhh[1]);
            const f16x8 bl0 = __builtin_bit_cast(f16x8, Bhl[0]);
            const f16x8 bl1 = __builtin_bit_cast(f16x8, Bhl[1]);
            const f16x8 bu00 = __builtin_bit_cast(f16x8, Bu0[0]);
            const f16x8 bu01 = __builtin_bit_cast(f16x8, Bu0[1]);
            const f16x8 bu10 = __builtin_bit_cast(f16x8, Bu1[0]);
            const f16x8 bu11 = __builtin_bit_cast(f16x8, Bu1[1]);

            const int hb = ht * 16 + qrt * 4;
            f32x4 Chi = *(const f32x4*)&cst[5][hb];   // init with b1a
            f32x4 Clo = {0.f,0.f,0.f,0.f};
            f32x4 Cz0 = {0.f,0.f,0.f,0.f};
            f32x4 Cz1 = {0.f,0.f,0.f,0.f};
            Chi = MFMA16(Ah0, bh0, Chi);  Chi = MFMA16(Ah1, bh1, Chi);
            Clo = MFMA16(Ah0, bl0, Clo);  Clo = MFMA16(Ah1, bl1, Clo);
            Clo = MFMA16(Al0, bh0, Clo);  Clo = MFMA16(Al1, bh1, Clo);
            Cz0 = MFMA16(Ah0, bu00, Cz0); Cz0 = MFMA16(Ah1, bu01, Cz0);
            Cz1 = MFMA16(Ah0, bu10, Cz1); Cz1 = MFMA16(Ah1, bu11, Cz1);

            const f32x4 w2a  = *(const f32x4*)&cst[0][hb];
            const f32x4 w2b  = *(const f32x4*)&cst[1][hb];
            const f32x4 w3a  = *(const f32x4*)&cst[2][hb];
            const f32x4 w3b  = *(const f32x4*)&cst[3][hb];
            const f32x4 w4v  = *(const f32x4*)&cst[4][hb];
#pragma unroll
            for (int r = 0; r < 4; ++r) {
                const float ah = fmaf(2.44140625e-4f, Clo[r], Chi[r]);
                const bool pos = ah > 0.0f;
                const float h2 = pos ? ah : 0.01f * ah;
                ag0 = fmaf(w2a[r], h2, ag0);   ag1 = fmaf(w2b[r], h2, ag1);
                al0 = fmaf(w3a[r], h2, al0);   al1 = fmaf(w3b[r], h2, al1);
                aoo = fmaf(w4v[r], h2, aoo);
                const float z0 = Cz0[r], z1 = Cz1[r];
                const float d0 = pos ? z0 : -0.01f * z0;
                const float d1 = pos ? z1 : -0.01f * z1;
                ap00 = fmaf(w3a[r], d0, ap00); ap01 = fmaf(w3a[r], d1, ap01);
                ap10 = fmaf(w3b[r], d0, ap10); ap11 = fmaf(w3b[r], d1, ap11);
                ar0  = fmaf(w4v[r], d0, ar0);  ar1  = fmaf(w4v[r], d1, ar1);
            }
        }

        // ---- Reduce over the 4 h-quarters (pure-VALU permlane swaps) ----
        ag0 = qsum(ag0); ag1 = qsum(ag1); al0 = qsum(al0); al1 = qsum(al1);
        aoo = qsum(aoo);
        ap00 = qsum(ap00); ap01 = qsum(ap01); ap10 = qsum(ap10); ap11 = qsum(ap11);
        ar0 = qsum(ar0);  ar1 = qsum(ar1);
        // Owner lane of sample t*16+p is lane t*16+p itself (qrt == t).
        if (qrt == t) {
            fg0 = ag0; fg1 = ag1; fl0 = al0; fl1 = al1; foo = aoo;
            fp00 = ap00; fp01 = ap01; fp10 = ap10; fp11 = ap11;
            fr0 = ar0; fr1 = ar1;
        }
    }

    // ---- Tail: biases + 2x2 algebra (identical to R1/R3) ----
    const float g0 = fg0 + b2[0], g1 = fg1 + b2[1];
    const float l0 = fl0 + b3[0], l1 = fl1 + b3[1];
    const float oo = foo + b4[0];
    const float p00 = fp00, p01 = fp01, p10 = fp10, p11 = fp11;
    const float r0 = fr0, r1 = fr1;

    const float ld0 = fmaxf(l0, 0.0f);
    const float ld1 = fmaxf(l1, 0.0f);
    const float dr30 = (l0 > 0.0f) ? 1.0f : 0.0f;
    const float dr31 = (l1 > 0.0f) ? 1.0f : 0.0f;

    const float da00 = dr30 * p00, da01 = dr30 * p01;
    const float da10 = dr31 * p10, da11 = dr31 * p11;

    const float l00 = ld0, l10 = oo, l11 = ld1;

    const float m00 = da00 * x2 + da01 * x3;
    const float m11 = da10 * x2 + da11 * x3;
    const float m10 = r0  * x2 + r1  * x3;

    const float eps = 1e-5f;
    const float Hm00 = fmaf(l00, l00, eps);
    const float Hm01 = l00 * l10;
    const float Hm11 = fmaf(l10, l10, fmaf(l11, l11, eps));

    const float dH00 = 2.0f * l00 * m00;
    const float dH01 = fmaf(l00, m10, l10 * m00);
    const float dH11 = 2.0f * fmaf(l10, m10, l11 * m11);

    const float x22 = x2 * x2, x23 = x2 * x3, x33 = x3 * x3;
    const float quad0 = 2.0f * (da00 * l00 * x22
                      + (fmaf(da00, l10, r0 * l00)) * x23
                      + (fmaf(r0, l10, da10 * l11)) * x33);
    const float quad1 = 2.0f * (da01 * l00 * x22
                      + (fmaf(da01, l10, r1 * l00)) * x23
                      + (fmaf(r1, l10, da11 * l11)) * x33);

    const float c0 = fmaf(dH00, x2, dH01 * x3) - 0.5f * quad0;
    const float c1 = fmaf(dH01, x2, dH11 * x3) - 0.5f * quad1;

    const float tau0 = fmaf(Hm00, x4, Hm01 * x5) + c0 + g0;
    const float tau1 = fmaf(Hm01, x4, Hm11 * x5) + c1 + g1;

    if (n < n_total) {
        const long long N = n_total;
        float2* tau_out = (float2*)(out) + n;
        float4* hm_out  = (float4*)(out + 2 * N) + n;
        float2* c_out   = (float2*)(out + 6 * N) + n;
        float2* g_out   = (float2*)(out + 8 * N) + n;
        *tau_out = make_float2(tau0, tau1);
        *hm_out  = make_float4(Hm00, Hm01, Hm01, Hm11);
        *c_out   = make_float2(c0, c1);
        *g_out   = make_float2(g0, g1);
    }
}

extern "C" void kernel_launch(void* const* d_in, const int* in_sizes, int n_in,
                              void* d_out, int out_size, void* d_ws, size_t ws_size,
                              hipStream_t stream) {
    const float* x   = (const float*)d_in[0];
    const float* W1  = (const float*)d_in[1];
    const float* b1  = (const float*)d_in[2];
    const float* W1a = (const float*)d_in[3];
    const float* b1a = (const float*)d_in[4];
    const float* W2  = (const float*)d_in[5];
    const float* b2  = (const float*)d_in[6];
    const float* W3  = (const float*)d_in[7];
    const float* b3  = (const float*)d_in[8];
    const float* W4  = (const float*)d_in[9];
    const float* b4  = (const float*)d_in[10];
    float* out = (float*)d_out;

    const int n_total = in_sizes[0] / 6;
    const int block = 256;
    const int grid = (n_total + block - 1) / block;
    delan_fwd<<<grid, block, 0, stream>>>(x, W1, b1, W1a, b1a, W2, b2,
                                          W3, b3, W4, b4, out, n_total);
}